// Round 13
// baseline (203.105 us; speedup 1.0000x reference)
//
#include <hip/hip_runtime.h>
#include <hip/hip_fp16.h>

#define N_NODES 50000
#define N_EDGES 800000
#define IN_CH 128
#define HID 64
#define HID2 32
#define BN_EPS 1e-5f

// ---------- FUSED: degrank (odd blocks) | gemm1-unscaled (even blocks) ----------
// LDS = As only (33.8 KB) -> 4 blocks/CU (was 2 with Ws; degrank waves were starved).
// W1 (32 KB, read-only, wave-broadcast) reads straight from L1.
__global__ __launch_bounds__(256) void k_degrank_gemm1(
        const int* __restrict__ ei, int* __restrict__ deg, unsigned short* __restrict__ rank,
        const float* __restrict__ x, const float* __restrict__ W1,
        __half* __restrict__ h1u, int E, int N) {
    __shared__ float As[64 * 132];     // rows 4 apart -> +16 banks (2-way free)
    int vb = blockIdx.x >> 1;
    if (blockIdx.x & 1) {
        // ---- degrank: deg[c]++ (rank = old count), coalesced ushort4 store ----
        int e = (vb * 256 + threadIdx.x) * 4;
        if (e >= E) return;
        int4 c4 = *(const int4*)(ei + E + e);
        ushort4 rk;
        rk.x = (unsigned short)atomicAdd(&deg[c4.x], 1);
        rk.y = (unsigned short)atomicAdd(&deg[c4.y], 1);
        rk.z = (unsigned short)atomicAdd(&deg[c4.z], 1);
        rk.w = (unsigned short)atomicAdd(&deg[c4.w], 1);
        *(ushort4*)(rank + e) = rk;
        return;
    }
    // ---- gemm1 (unscaled): h1u[n][f] = fp16( sum_k x[n][k]*W1[k][f] ) ----
    int tid = threadIdx.x;
    int n0 = vb * 64;
#pragma unroll
    for (int idx = tid; idx < 64 * IN_CH / 4; idx += 256) {
        int r = idx / (IN_CH / 4), c = idx % (IN_CH / 4);
        int n = n0 + r; if (n > N - 1) n = N - 1;
        float4 v = *(const float4*)(x + (size_t)n * IN_CH + c * 4);
        *(float4*)(As + r * 132 + c * 4) = v;
    }
    __syncthreads();
    int tn = tid % (HID / 4), tm = tid / (HID / 4);
    int na = tm * 4, fb = tn * 4;
    float acc[4][4] = {};
#pragma unroll 4
    for (int k = 0; k < IN_CH; k += 4) {
        float4 a[4], b[4];
#pragma unroll
        for (int i = 0; i < 4; ++i) a[i] = *(const float4*)(As + (na + i) * 132 + k);
#pragma unroll
        for (int j = 0; j < 4; ++j) b[j] = *(const float4*)(W1 + (k + j) * HID + fb);
#pragma unroll
        for (int i = 0; i < 4; ++i) {
            acc[i][0] = fmaf(a[i].x, b[0].x, acc[i][0]);
            acc[i][1] = fmaf(a[i].x, b[0].y, acc[i][1]);
            acc[i][2] = fmaf(a[i].x, b[0].z, acc[i][2]);
            acc[i][3] = fmaf(a[i].x, b[0].w, acc[i][3]);
            acc[i][0] = fmaf(a[i].y, b[1].x, acc[i][0]);
            acc[i][1] = fmaf(a[i].y, b[1].y, acc[i][1]);
            acc[i][2] = fmaf(a[i].y, b[1].z, acc[i][2]);
            acc[i][3] = fmaf(a[i].y, b[1].w, acc[i][3]);
            acc[i][0] = fmaf(a[i].z, b[2].x, acc[i][0]);
            acc[i][1] = fmaf(a[i].z, b[2].y, acc[i][1]);
            acc[i][2] = fmaf(a[i].z, b[2].z, acc[i][2]);
            acc[i][3] = fmaf(a[i].z, b[2].w, acc[i][3]);
            acc[i][0] = fmaf(a[i].w, b[3].x, acc[i][0]);
            acc[i][1] = fmaf(a[i].w, b[3].y, acc[i][1]);
            acc[i][2] = fmaf(a[i].w, b[3].z, acc[i][2]);
            acc[i][3] = fmaf(a[i].w, b[3].w, acc[i][3]);
        }
    }
#pragma unroll
    for (int i = 0; i < 4; ++i) {
        int n = n0 + na + i;
        if (n < N) {
            union { __half2 h2[2]; uint2 u; } uu;
            uu.h2[0] = __floats2half2_rn(acc[i][0], acc[i][1]);
            uu.h2[1] = __floats2half2_rn(acc[i][2], acc[i][3]);
            *(uint2*)(h1u + (size_t)n * HID + fb) = uu.u;
        }
    }
}

// ---------- scan stage 1: block sums + dinv ----------
__global__ __launch_bounds__(256) void k_scan1(const int* __restrict__ deg, int* __restrict__ bsum,
                                               float* __restrict__ dinv, int N) {
    __shared__ int s[256];
    int i = blockIdx.x * 256 + threadIdx.x, t = threadIdx.x;
    int d = (i < N) ? deg[i] : 0;
    if (i < N) dinv[i] = rsqrtf((float)d + 1.0f);  // +1 = self loop
    s[t] = d;
    __syncthreads();
    for (int off = 128; off > 0; off >>= 1) {
        if (t < off) s[t] += s[t + off];
        __syncthreads();
    }
    if (t == 0) bsum[blockIdx.x] = s[0];
}

// ---------- scan stage 2 (fused): block reduces its prefix of bsum, then local scan ----------
__global__ __launch_bounds__(256) void k_scan3(const int* __restrict__ deg, const int* __restrict__ bsum,
                                               int* __restrict__ offs, int N, int NB) {
    __shared__ int s[256];
    __shared__ int p[256];
    int i = blockIdx.x * 256 + threadIdx.x, t = threadIdx.x;
    int v = (i < N) ? deg[i] : 0;
    p[t] = (t < blockIdx.x && t < NB) ? bsum[t] : 0;   // NB<=256
    s[t] = v;
    __syncthreads();
    for (int off = 128; off > 0; off >>= 1) {
        if (t < off) p[t] += p[t + off];
        __syncthreads();
    }
    int pref = p[0];
    for (int off = 1; off < 256; off <<= 1) {
        int u = (t >= off) ? s[t - off] : 0;
        __syncthreads(); s[t] += u; __syncthreads();
    }
    if (i < N) offs[i] = pref + s[t] - v;              // exclusive
    if (i == N - 1) offs[N] = pref + s[t];             // total == E
}

// ---------- FUSED: h1 scale (even blocks) | fillr (odd blocks) — both LDS-free ----------
__global__ __launch_bounds__(256) void k_fillr_scale(
        const int* __restrict__ ei, const unsigned short* __restrict__ rank,
        const int* __restrict__ offs, unsigned short* __restrict__ csr,
        __half* __restrict__ h1p, const float* __restrict__ dinv, int E, int N, int EB) {
    int vb = blockIdx.x >> 1;
    if (blockIdx.x & 1) {
        // ---- fillr: csr[offs[c]+rank[e]] = row ----
        if (vb >= EB) return;
        int e = (vb * 256 + threadIdx.x) * 4;
        if (e >= E) return;
        int4 r4 = *(const int4*)(ei + e);
        int4 c4 = *(const int4*)(ei + E + e);
        ushort4 k4 = *(const ushort4*)(rank + e);
        csr[offs[c4.x] + k4.x] = (unsigned short)r4.x;
        csr[offs[c4.y] + k4.y] = (unsigned short)r4.y;
        csr[offs[c4.z] + k4.z] = (unsigned short)r4.z;
        csr[offs[c4.w] + k4.w] = (unsigned short)r4.w;
        return;
    }
    // ---- scale: h1p[n][*] *= dinv[n], 8 halves (uint4) per thread, in place ----
    int idx = vb * 256 + threadIdx.x;
    if (idx >= N * HID / 8) return;
    int n = idx >> 3;                  // 8 chunks of 8 halves per 64-wide row
    float dn = dinv[n];
    union { uint4 u; __half2 h[4]; } v;
    v.u = *(const uint4*)(h1p + (size_t)idx * 8);
#pragma unroll
    for (int q = 0; q < 4; ++q) {
        float2 f = __half22float2(v.h[q]);
        v.h[q] = __floats2half2_rn(f.x * dn, f.y * dn);
    }
    *(uint4*)(h1p + (size_t)idx * 8) = v.u;
}

// ---------- gather layer 1: 8 nodes/wave, lane = 8 feats (uint4) + BN/ReLU + fused gemm2 ----------
__global__ __launch_bounds__(256) void k_gather1(const __half* __restrict__ h1p, const int* __restrict__ offs,
                                                 const unsigned short* __restrict__ csr, const float* __restrict__ dinv,
                                                 const float* __restrict__ b1, const float* __restrict__ g1,
                                                 const float* __restrict__ be1, const float* __restrict__ rm1,
                                                 const float* __restrict__ rv1, const float* __restrict__ W2,
                                                 __half* __restrict__ h2p, int N) {
    __shared__ float W2s[HID * HID2];  // row-major [k][f], 8 KB; reads are 8-way broadcast
    for (int idx = threadIdx.x; idx < HID * HID2; idx += 256) W2s[idx] = W2[idx];
    __syncthreads();
    int wid = (blockIdx.x * 256 + threadIdx.x) >> 6;
    int lane = threadIdx.x & 63;
    int sub = lane >> 3;              // node slot 0..7
    int l8 = lane & 7;
    int fl = l8 << 3;                 // feature base (halves) 0..56
    int nd = wid * 8 + sub;
    bool ok = nd < N;
    if (!ok) nd = N - 1;
    int start = offs[nd], end = offs[nd + 1];
    float acc[8];
    {   // self loop
        union { uint4 u; __half2 h[4]; } v;
        v.u = *(const uint4*)(h1p + ((size_t)nd << 6) + fl);
#pragma unroll
        for (int q = 0; q < 4; ++q) {
            float2 f = __half22float2(v.h[q]);
            acc[2 * q] = f.x; acc[2 * q + 1] = f.y;
        }
    }
    int sb = sub << 3;
    for (int j = start; j < end; j += 8) {
        int rid = (j + l8 < end) ? (int)csr[j + l8] : 0;
        int cnt = end - j; if (cnt > 8) cnt = 8;
        int t = 0;
        for (; t + 7 < cnt; t += 8) {   // cnt==8 full chunk
            int r0 = __shfl(rid, sb + 0, 64), r1 = __shfl(rid, sb + 1, 64);
            int r2 = __shfl(rid, sb + 2, 64), r3 = __shfl(rid, sb + 3, 64);
            int r4 = __shfl(rid, sb + 4, 64), r5 = __shfl(rid, sb + 5, 64);
            int r6 = __shfl(rid, sb + 6, 64), r7 = __shfl(rid, sb + 7, 64);
            union { uint4 u; __half2 h[4]; } v0, v1, v2, v3, v4, v5, v6, v7;
            v0.u = *(const uint4*)(h1p + ((size_t)r0 << 6) + fl);
            v1.u = *(const uint4*)(h1p + ((size_t)r1 << 6) + fl);
            v2.u = *(const uint4*)(h1p + ((size_t)r2 << 6) + fl);
            v3.u = *(const uint4*)(h1p + ((size_t)r3 << 6) + fl);
            v4.u = *(const uint4*)(h1p + ((size_t)r4 << 6) + fl);
            v5.u = *(const uint4*)(h1p + ((size_t)r5 << 6) + fl);
            v6.u = *(const uint4*)(h1p + ((size_t)r6 << 6) + fl);
            v7.u = *(const uint4*)(h1p + ((size_t)r7 << 6) + fl);
#pragma unroll
            for (int q = 0; q < 4; ++q) {
                float2 f0 = __half22float2(v0.h[q]), f1 = __half22float2(v1.h[q]);
                float2 f2 = __half22float2(v2.h[q]), f3 = __half22float2(v3.h[q]);
                float2 f4 = __half22float2(v4.h[q]), f5 = __half22float2(v5.h[q]);
                float2 f6 = __half22float2(v6.h[q]), f7 = __half22float2(v7.h[q]);
                acc[2 * q]     += ((f0.x + f1.x) + (f2.x + f3.x)) + ((f4.x + f5.x) + (f6.x + f7.x));
                acc[2 * q + 1] += ((f0.y + f1.y) + (f2.y + f3.y)) + ((f4.y + f5.y) + (f6.y + f7.y));
            }
        }
        for (; t < cnt; ++t) {
            int r = __shfl(rid, sb + t, 64);
            union { uint4 u; __half2 h[4]; } v;
            v.u = *(const uint4*)(h1p + ((size_t)r << 6) + fl);
#pragma unroll
            for (int q = 0; q < 4; ++q) {
                float2 f = __half22float2(v.h[q]);
                acc[2 * q] += f.x; acc[2 * q + 1] += f.y;
            }
        }
    }
    float dn = dinv[nd];
    float o[8];
    {
        float4 bbA = *(const float4*)(b1 + fl),  bbB = *(const float4*)(b1 + fl + 4);
        float4 ggA = *(const float4*)(g1 + fl),  ggB = *(const float4*)(g1 + fl + 4);
        float4 eeA = *(const float4*)(be1 + fl), eeB = *(const float4*)(be1 + fl + 4);
        float4 mmA = *(const float4*)(rm1 + fl), mmB = *(const float4*)(rm1 + fl + 4);
        float4 vvA = *(const float4*)(rv1 + fl), vvB = *(const float4*)(rv1 + fl + 4);
        const float* bb = &bbA.x; const float* gg = &ggA.x; const float* ee = &eeA.x;
        const float* mm = &mmA.x; const float* vv = &vvA.x;
        float b8[8] = {bbA.x, bbA.y, bbA.z, bbA.w, bbB.x, bbB.y, bbB.z, bbB.w};
        float g8[8] = {ggA.x, ggA.y, ggA.z, ggA.w, ggB.x, ggB.y, ggB.z, ggB.w};
        float e8[8] = {eeA.x, eeA.y, eeA.z, eeA.w, eeB.x, eeB.y, eeB.z, eeB.w};
        float m8[8] = {mmA.x, mmA.y, mmA.z, mmA.w, mmB.x, mmB.y, mmB.z, mmB.w};
        float v8[8] = {vvA.x, vvA.y, vvA.z, vvA.w, vvB.x, vvB.y, vvB.z, vvB.w};
        (void)bb; (void)gg; (void)ee; (void)mm; (void)vv;
#pragma unroll
        for (int q = 0; q < 8; ++q)
            o[q] = fmaxf((dn * acc[q] + b8[q] - m8[q]) * (g8[q] * rsqrtf(v8[q] + BN_EPS)) + e8[q], 0.f);
    }
    // ---- fused gemm2: 4 outputs/lane (features l8*4..+3) ----
    float r0 = 0.f, r1 = 0.f, r2 = 0.f, r3 = 0.f;
    int fo = l8 << 2;
#pragma unroll
    for (int k4 = 0; k4 < 8; ++k4) {
        int src = sb + k4;
        float a[8];
#pragma unroll
        for (int q = 0; q < 8; ++q) a[q] = __shfl(o[q], src, 64);
        int kb = k4 << 3;
#pragma unroll
        for (int kk = 0; kk < 8; ++kk) {
            float4 w = *(const float4*)&W2s[(kb + kk) * HID2 + fo];
            r0 = fmaf(a[kk], w.x, r0);
            r1 = fmaf(a[kk], w.y, r1);
            r2 = fmaf(a[kk], w.z, r2);
            r3 = fmaf(a[kk], w.w, r3);
        }
    }
    if (ok) {
        union { __half2 h[2]; uint2 u; } uu;
        uu.h[0] = __floats2half2_rn(dn * r0, dn * r1);
        uu.h[1] = __floats2half2_rn(dn * r2, dn * r3);
        *(uint2*)(h2p + ((size_t)nd << 5) + fo) = uu.u;
    }
}

// ---------- gather layer 2 (fp16 rows): 8 nodes/wave, lane = 4 feats + fused FC ----------
__global__ __launch_bounds__(256) void k_gather2(const __half* __restrict__ h2p, const int* __restrict__ offs,
                                                 const unsigned short* __restrict__ csr, const float* __restrict__ dinv,
                                                 const float* __restrict__ b2, const float* __restrict__ g2,
                                                 const float* __restrict__ be2, const float* __restrict__ rm2,
                                                 const float* __restrict__ rv2, const float* __restrict__ fcW,
                                                 const float* __restrict__ fcb, float* __restrict__ out, int N) {
    int wid = (blockIdx.x * 256 + threadIdx.x) >> 6;
    int lane = threadIdx.x & 63;
    int sub = lane >> 3;              // node slot 0..7
    int l8 = lane & 7;
    int fl = l8 << 2;                 // feature base 0..28
    int nd = wid * 8 + sub;
    bool ok = nd < N;
    if (!ok) nd = N - 1;
    int start = offs[nd], end = offs[nd + 1];
    float4 acc;
    {   // self loop
        union { uint2 u; __half2 h[2]; } v;
        v.u = *(const uint2*)(h2p + ((size_t)nd << 5) + fl);
        float2 f0 = __half22float2(v.h[0]), f1 = __half22float2(v.h[1]);
        acc = make_float4(f0.x, f0.y, f1.x, f1.y);
    }
    int sb = sub << 3;
    for (int j = start; j < end; j += 8) {
        int rid = (j + l8 < end) ? (int)csr[j + l8] : 0;
        int cnt = end - j; if (cnt > 8) cnt = 8;
        int t = 0;
        for (; t + 7 < cnt; t += 8) {
            int r0 = __shfl(rid, sb + 0, 64), r1 = __shfl(rid, sb + 1, 64);
            int r2 = __shfl(rid, sb + 2, 64), r3 = __shfl(rid, sb + 3, 64);
            int r4 = __shfl(rid, sb + 4, 64), r5 = __shfl(rid, sb + 5, 64);
            int r6 = __shfl(rid, sb + 6, 64), r7 = __shfl(rid, sb + 7, 64);
            union { uint2 u; __half2 h[2]; } v0, v1, v2, v3, v4, v5, v6, v7;
            v0.u = *(const uint2*)(h2p + ((size_t)r0 << 5) + fl);
            v1.u = *(const uint2*)(h2p + ((size_t)r1 << 5) + fl);
            v2.u = *(const uint2*)(h2p + ((size_t)r2 << 5) + fl);
            v3.u = *(const uint2*)(h2p + ((size_t)r3 << 5) + fl);
            v4.u = *(const uint2*)(h2p + ((size_t)r4 << 5) + fl);
            v5.u = *(const uint2*)(h2p + ((size_t)r5 << 5) + fl);
            v6.u = *(const uint2*)(h2p + ((size_t)r6 << 5) + fl);
            v7.u = *(const uint2*)(h2p + ((size_t)r7 << 5) + fl);
            float2 a0 = __half22float2(v0.h[0]), a1 = __half22float2(v1.h[0]);
            float2 a2 = __half22float2(v2.h[0]), a3 = __half22float2(v3.h[0]);
            float2 a4 = __half22float2(v4.h[0]), a5 = __half22float2(v5.h[0]);
            float2 a6 = __half22float2(v6.h[0]), a7 = __half22float2(v7.h[0]);
            acc.x += ((a0.x + a1.x) + (a2.x + a3.x)) + ((a4.x + a5.x) + (a6.x + a7.x));
            acc.y += ((a0.y + a1.y) + (a2.y + a3.y)) + ((a4.y + a5.y) + (a6.y + a7.y));
            float2 c0 = __half22float2(v0.h[1]), c1 = __half22float2(v1.h[1]);
            float2 c2 = __half22float2(v2.h[1]), c3 = __half22float2(v3.h[1]);
            float2 c4 = __half22float2(v4.h[1]), c5 = __half22float2(v5.h[1]);
            float2 c6 = __half22float2(v6.h[1]), c7 = __half22float2(v7.h[1]);
            acc.z += ((c0.x + c1.x) + (c2.x + c3.x)) + ((c4.x + c5.x) + (c6.x + c7.x));
            acc.w += ((c0.y + c1.y) + (c2.y + c3.y)) + ((c4.y + c5.y) + (c6.y + c7.y));
        }
        for (; t < cnt; ++t) {
            int r = __shfl(rid, sb + t, 64);
            union { uint2 u; __half2 h[2]; } v;
            v.u = *(const uint2*)(h2p + ((size_t)r << 5) + fl);
            float2 f0 = __half22float2(v.h[0]), f1 = __half22float2(v.h[1]);
            acc.x += f0.x; acc.y += f0.y; acc.z += f1.x; acc.w += f1.y;
        }
    }
    float dn = dinv[nd];
    float4 bb = *(const float4*)(b2 + fl);
    float4 gg = *(const float4*)(g2 + fl);
    float4 ee = *(const float4*)(be2 + fl);
    float4 mm = *(const float4*)(rm2 + fl);
    float4 vv = *(const float4*)(rv2 + fl);
    float4 ww = *(const float4*)(fcW + fl);
    float s;
    s  = fmaxf((dn * acc.x + bb.x - mm.x) * (gg.x * rsqrtf(vv.x + BN_EPS)) + ee.x, 0.f) * ww.x;
    s += fmaxf((dn * acc.y + bb.y - mm.y) * (gg.y * rsqrtf(vv.y + BN_EPS)) + ee.y, 0.f) * ww.y;
    s += fmaxf((dn * acc.z + bb.z - mm.z) * (gg.z * rsqrtf(vv.z + BN_EPS)) + ee.z, 0.f) * ww.z;
    s += fmaxf((dn * acc.w + bb.w - mm.w) * (gg.w * rsqrtf(vv.w + BN_EPS)) + ee.w, 0.f) * ww.w;
    s += __shfl_down(s, 4, 8);
    s += __shfl_down(s, 2, 8);
    s += __shfl_down(s, 1, 8);
    if (ok && l8 == 0) out[nd] = s + fcb[0];
}

extern "C" void kernel_launch(void* const* d_in, const int* in_sizes, int n_in,
                              void* d_out, int out_size, void* d_ws, size_t ws_size,
                              hipStream_t stream) {
    const float* x   = (const float*)d_in[0];
    const int*   ei  = (const int*)d_in[1];
    const float* W1  = (const float*)d_in[2];
    const float* b1  = (const float*)d_in[3];
    const float* W2  = (const float*)d_in[4];
    const float* b2  = (const float*)d_in[5];
    const float* fcW = (const float*)d_in[6];
    const float* fcb = (const float*)d_in[7];
    const float* g1  = (const float*)d_in[8];
    const float* be1 = (const float*)d_in[9];
    const float* rm1 = (const float*)d_in[10];
    const float* rv1 = (const float*)d_in[11];
    const float* g2  = (const float*)d_in[12];
    const float* be2 = (const float*)d_in[13];
    const float* rm2 = (const float*)d_in[14];
    const float* rv2 = (const float*)d_in[15];
    float* out = (float*)d_out;

    const int N = N_NODES, E = N_EDGES;
    const int NB = (N + 255) / 256;           // 196 scan blocks
    const int EB = (E / 4 + 255) / 256;       // 782 edge blocks
    const int GB = (N + 63) / 64;             // 782 gemm1 blocks (== EB)
    const int SB = (N * HID / 8 + 255) / 256; // 1563 scale blocks

    char* base = (char*)d_ws;
    int*            deg  = (int*)(base);                      // N ints
    int*            offs = (int*)(base + 200704);             // N+1 ints
    float*          dinv = (float*)(base + 401408);           // N floats
    int*            bsum = (int*)(base + 602112);             // 256 ints
    unsigned short* rank = (unsigned short*)(base + 603136);  // E ushort (1.6 MB)
    unsigned short* csr  = (unsigned short*)(base + 2203136); // E ushort (1.6 MB)
    __half*         h1p  = (__half*)(base + 3803136);         // N*64 halves (6.4 MB)
    __half*         h2p  = (__half*)(base + 10203136);        // N*32 halves (3.2 MB)

    hipMemsetAsync(deg, 0, (size_t)N * sizeof(int), stream);

    // fused: even blocks = gemm1-unscaled (GB), odd blocks = degrank (EB); EB == GB
    k_degrank_gemm1<<<EB + GB, 256, 0, stream>>>(ei, deg, rank, x, W1, h1p, E, N);
    k_scan1<<<NB, 256, 0, stream>>>(deg, bsum, dinv, N);
    k_scan3<<<NB, 256, 0, stream>>>(deg, bsum, offs, N, NB);
    // fused: even blocks = h1 scale (SB), odd blocks = fillr (EB)
    k_fillr_scale<<<2 * SB, 256, 0, stream>>>(ei, rank, offs, csr, h1p, dinv, E, N, EB);

    k_gather1<<<((N + 7) / 8 * 64 + 255) / 256, 256, 0, stream>>>(h1p, offs, csr, dinv, b1, g1, be1, rm1, rv1, W2, h2p, N);
    k_gather2<<<((N + 7) / 8 * 64 + 255) / 256, 256, 0, stream>>>(h2p, offs, csr, dinv, b2, g2, be2, rm2, rv2, fcW, fcb, out, N);
}

// Round 14
// 195.676 us; speedup vs baseline: 1.0380x; 1.0380x over previous
//
#include <hip/hip_runtime.h>
#include <hip/hip_fp16.h>

#define N_NODES 50000
#define N_EDGES 800000
#define IN_CH 128
#define HID 64
#define HID2 32
#define BN_EPS 1e-5f
#define NP 50176   // N rounded to 256

// ---------- FUSED: degrank (odd blocks) | gemm1-unscaled (even blocks) ----------
// 4-way split deg counters: plane p = edge index % 4 -> per-address atomic chains 16 -> 4.
__global__ __launch_bounds__(256) void k_degrank_gemm1(
        const int* __restrict__ ei, int* __restrict__ deg4, unsigned short* __restrict__ rank,
        const float* __restrict__ x, const float* __restrict__ W1,
        __half* __restrict__ h1u, int E, int N) {
    __shared__ float As[64 * 132];     // rows 4 apart -> +16 banks (2-way free)
    __shared__ float Ws[IN_CH * HID];  // 32 KB (L1 thrashes without it — R13 evidence)
    int vb = blockIdx.x >> 1;
    if (blockIdx.x & 1) {
        int e = (vb * 256 + threadIdx.x) * 4;
        if (e >= E) return;
        int4 c4 = *(const int4*)(ei + E + e);
        ushort4 rk;
        rk.x = (unsigned short)atomicAdd(&deg4[0 * NP + c4.x], 1);
        rk.y = (unsigned short)atomicAdd(&deg4[1 * NP + c4.y], 1);
        rk.z = (unsigned short)atomicAdd(&deg4[2 * NP + c4.z], 1);
        rk.w = (unsigned short)atomicAdd(&deg4[3 * NP + c4.w], 1);
        *(ushort4*)(rank + e) = rk;
        return;
    }
    // ---- gemm1 (unscaled): h1u[n][f] = fp16( sum_k x[n][k]*W1[k][f] ) ----
    int tid = threadIdx.x;
    int n0 = vb * 64;
#pragma unroll
    for (int idx = tid; idx < 64 * IN_CH / 4; idx += 256) {
        int r = idx / (IN_CH / 4), c = idx % (IN_CH / 4);
        int n = n0 + r; if (n > N - 1) n = N - 1;
        float4 v = *(const float4*)(x + (size_t)n * IN_CH + c * 4);
        *(float4*)(As + r * 132 + c * 4) = v;
    }
#pragma unroll
    for (int idx = tid; idx < IN_CH * HID / 4; idx += 256) {
        *(float4*)(Ws + idx * 4) = *(const float4*)(W1 + idx * 4);
    }
    __syncthreads();
    int tn = tid % (HID / 4), tm = tid / (HID / 4);
    int na = tm * 4, fb = tn * 4;
    float acc[4][4] = {};
#pragma unroll 4
    for (int k = 0; k < IN_CH; k += 4) {
        float4 a[4], b[4];
#pragma unroll
        for (int i = 0; i < 4; ++i) a[i] = *(const float4*)(As + (na + i) * 132 + k);
#pragma unroll
        for (int j = 0; j < 4; ++j) b[j] = *(const float4*)(Ws + (k + j) * HID + fb);
#pragma unroll
        for (int i = 0; i < 4; ++i) {
            acc[i][0] = fmaf(a[i].x, b[0].x, acc[i][0]);
            acc[i][1] = fmaf(a[i].x, b[0].y, acc[i][1]);
            acc[i][2] = fmaf(a[i].x, b[0].z, acc[i][2]);
            acc[i][3] = fmaf(a[i].x, b[0].w, acc[i][3]);
            acc[i][0] = fmaf(a[i].y, b[1].x, acc[i][0]);
            acc[i][1] = fmaf(a[i].y, b[1].y, acc[i][1]);
            acc[i][2] = fmaf(a[i].y, b[1].z, acc[i][2]);
            acc[i][3] = fmaf(a[i].y, b[1].w, acc[i][3]);
            acc[i][0] = fmaf(a[i].z, b[2].x, acc[i][0]);
            acc[i][1] = fmaf(a[i].z, b[2].y, acc[i][1]);
            acc[i][2] = fmaf(a[i].z, b[2].z, acc[i][2]);
            acc[i][3] = fmaf(a[i].z, b[2].w, acc[i][3]);
            acc[i][0] = fmaf(a[i].w, b[3].x, acc[i][0]);
            acc[i][1] = fmaf(a[i].w, b[3].y, acc[i][1]);
            acc[i][2] = fmaf(a[i].w, b[3].z, acc[i][2]);
            acc[i][3] = fmaf(a[i].w, b[3].w, acc[i][3]);
        }
    }
#pragma unroll
    for (int i = 0; i < 4; ++i) {
        int n = n0 + na + i;
        if (n < N) {
            union { __half2 h2[2]; uint2 u; } uu;
            uu.h2[0] = __floats2half2_rn(acc[i][0], acc[i][1]);
            uu.h2[1] = __floats2half2_rn(acc[i][2], acc[i][3]);
            *(uint2*)(h1u + (size_t)n * HID + fb) = uu.u;
        }
    }
}

// ---------- scan stage 1: block sums (over 4-plane deg) + dinv ----------
__global__ __launch_bounds__(256) void k_scan1(const int* __restrict__ deg4, int* __restrict__ bsum,
                                               float* __restrict__ dinv, int N) {
    __shared__ int s[256];
    int i = blockIdx.x * 256 + threadIdx.x, t = threadIdx.x;
    int d = 0;
    if (i < N) {
        d = deg4[i] + deg4[NP + i] + deg4[2 * NP + i] + deg4[3 * NP + i];
        dinv[i] = rsqrtf((float)d + 1.0f);  // +1 = self loop
    }
    s[t] = d;
    __syncthreads();
    for (int off = 128; off > 0; off >>= 1) {
        if (t < off) s[t] += s[t + off];
        __syncthreads();
    }
    if (t == 0) bsum[blockIdx.x] = s[0];
}

// ---------- scan stage 2 (fused): prefix over bsum + local scan + off4 for fillr ----------
__global__ __launch_bounds__(256) void k_scan3(const int* __restrict__ deg4, const int* __restrict__ bsum,
                                               int* __restrict__ offs, int4* __restrict__ off4, int N, int NB) {
    __shared__ int s[256];
    __shared__ int p[256];
    int i = blockIdx.x * 256 + threadIdx.x, t = threadIdx.x;
    int d0 = 0, d1 = 0, d2 = 0, d3 = 0;
    if (i < N) {
        d0 = deg4[i]; d1 = deg4[NP + i]; d2 = deg4[2 * NP + i]; d3 = deg4[3 * NP + i];
    }
    int v = d0 + d1 + d2 + d3;
    p[t] = (t < blockIdx.x && t < NB) ? bsum[t] : 0;   // NB<=256
    s[t] = v;
    __syncthreads();
    for (int off = 128; off > 0; off >>= 1) {
        if (t < off) p[t] += p[t + off];
        __syncthreads();
    }
    int pref = p[0];
    for (int off = 1; off < 256; off <<= 1) {
        int u = (t >= off) ? s[t - off] : 0;
        __syncthreads(); s[t] += u; __syncthreads();
    }
    if (i < N) {
        int ex = pref + s[t] - v;
        offs[i] = ex;                                  // exclusive
        off4[i] = make_int4(ex, ex + d0, ex + d0 + d1, ex + d0 + d1 + d2);
    }
    if (i == N - 1) offs[N] = pref + s[t];             // total == E
}

// ---------- FUSED: h1 scale (even blocks) | fillr (odd blocks) — both LDS-free ----------
__global__ __launch_bounds__(256) void k_fillr_scale(
        const int* __restrict__ ei, const unsigned short* __restrict__ rank,
        const int4* __restrict__ off4, unsigned short* __restrict__ csr,
        __half* __restrict__ h1p, const float* __restrict__ dinv, int E, int N, int EB) {
    int vb = blockIdx.x >> 1;
    if (blockIdx.x & 1) {
        // ---- fillr: csr[off4[c][plane] + rank[e]] = row ----
        if (vb >= EB) return;
        int e = (vb * 256 + threadIdx.x) * 4;
        if (e >= E) return;
        int4 r4 = *(const int4*)(ei + e);
        int4 c4 = *(const int4*)(ei + E + e);
        ushort4 k4 = *(const ushort4*)(rank + e);
        csr[off4[c4.x].x + k4.x] = (unsigned short)r4.x;   // plane 0
        csr[off4[c4.y].y + k4.y] = (unsigned short)r4.y;   // plane 1
        csr[off4[c4.z].z + k4.z] = (unsigned short)r4.z;   // plane 2
        csr[off4[c4.w].w + k4.w] = (unsigned short)r4.w;   // plane 3
        return;
    }
    // ---- scale: h1p[n][*] *= dinv[n], 8 halves (uint4) per thread, in place ----
    int idx = vb * 256 + threadIdx.x;
    if (idx >= N * HID / 8) return;
    int n = idx >> 3;                  // 8 chunks of 8 halves per 64-wide row
    float dn = dinv[n];
    union { uint4 u; __half2 h[4]; } v;
    v.u = *(const uint4*)(h1p + (size_t)idx * 8);
#pragma unroll
    for (int q = 0; q < 4; ++q) {
        float2 f = __half22float2(v.h[q]);
        v.h[q] = __floats2half2_rn(f.x * dn, f.y * dn);
    }
    *(uint4*)(h1p + (size_t)idx * 8) = v.u;
}

// ---------- gather layer 1 (fp16 rows) + BN + ReLU + fused gemm2 -> h2p (fp16) ----------
// 4 nodes/wave; 16-lane subgroup = node's 64 feats (4/lane). Row read = uint2 (8B).
__global__ __launch_bounds__(256) void k_gather1(const __half* __restrict__ h1p, const int* __restrict__ offs,
                                                 const unsigned short* __restrict__ csr, const float* __restrict__ dinv,
                                                 const float* __restrict__ b1, const float* __restrict__ g1,
                                                 const float* __restrict__ be1, const float* __restrict__ rm1,
                                                 const float* __restrict__ rv1, const float* __restrict__ W2,
                                                 __half* __restrict__ h2p, int N) {
    __shared__ float W2p[HID * HID2];  // paired layout: W2p[k*32 + l*2 + j] = W2[k*32 + l + 16*j]
    {
        int tid = threadIdx.x;
        for (int idx = tid; idx < HID * HID2; idx += 256) {
            int k = idx >> 5, f = idx & 31;
            W2p[(k << 5) | ((f & 15) << 1) | (f >> 4)] = W2[idx];
        }
    }
    __syncthreads();
    int wid = (blockIdx.x * 256 + threadIdx.x) >> 6;
    int lane = threadIdx.x & 63;
    int sub = lane >> 4;              // node slot 0..3
    int l16 = lane & 15;
    int fl = l16 << 2;                // feature base
    int nd = wid * 4 + sub;           // grid exact: nd < N (N%4==0)
    int start = offs[nd], end = offs[nd + 1];
    float4 acc;
    {   // self loop
        union { uint2 u; __half2 h[2]; } v;
        v.u = *(const uint2*)(h1p + ((size_t)nd << 6) + fl);
        float2 f0 = __half22float2(v.h[0]), f1 = __half22float2(v.h[1]);
        acc = make_float4(f0.x, f0.y, f1.x, f1.y);
    }
    int sb = sub << 4;
    for (int j = start; j < end; j += 16) {
        int rid = (j + l16 < end) ? (int)csr[j + l16] : 0;
        int cnt = end - j; if (cnt > 16) cnt = 16;
        int t = 0;
        for (; t + 7 < cnt; t += 8) {
            int r0 = __shfl(rid, sb + t + 0, 64), r1 = __shfl(rid, sb + t + 1, 64);
            int r2 = __shfl(rid, sb + t + 2, 64), r3 = __shfl(rid, sb + t + 3, 64);
            int r4 = __shfl(rid, sb + t + 4, 64), r5 = __shfl(rid, sb + t + 5, 64);
            int r6 = __shfl(rid, sb + t + 6, 64), r7 = __shfl(rid, sb + t + 7, 64);
            union { uint2 u; __half2 h[2]; } v0, v1, v2, v3, v4, v5, v6, v7;
            v0.u = *(const uint2*)(h1p + ((size_t)r0 << 6) + fl);
            v1.u = *(const uint2*)(h1p + ((size_t)r1 << 6) + fl);
            v2.u = *(const uint2*)(h1p + ((size_t)r2 << 6) + fl);
            v3.u = *(const uint2*)(h1p + ((size_t)r3 << 6) + fl);
            v4.u = *(const uint2*)(h1p + ((size_t)r4 << 6) + fl);
            v5.u = *(const uint2*)(h1p + ((size_t)r5 << 6) + fl);
            v6.u = *(const uint2*)(h1p + ((size_t)r6 << 6) + fl);
            v7.u = *(const uint2*)(h1p + ((size_t)r7 << 6) + fl);
            float2 a0 = __half22float2(v0.h[0]), a1 = __half22float2(v1.h[0]);
            float2 a2 = __half22float2(v2.h[0]), a3 = __half22float2(v3.h[0]);
            float2 a4 = __half22float2(v4.h[0]), a5 = __half22float2(v5.h[0]);
            float2 a6 = __half22float2(v6.h[0]), a7 = __half22float2(v7.h[0]);
            acc.x += ((a0.x + a1.x) + (a2.x + a3.x)) + ((a4.x + a5.x) + (a6.x + a7.x));
            acc.y += ((a0.y + a1.y) + (a2.y + a3.y)) + ((a4.y + a5.y) + (a6.y + a7.y));
            float2 c0 = __half22float2(v0.h[1]), c1 = __half22float2(v1.h[1]);
            float2 c2 = __half22float2(v2.h[1]), c3 = __half22float2(v3.h[1]);
            float2 c4 = __half22float2(v4.h[1]), c5 = __half22float2(v5.h[1]);
            float2 c6 = __half22float2(v6.h[1]), c7 = __half22float2(v7.h[1]);
            acc.z += ((c0.x + c1.x) + (c2.x + c3.x)) + ((c4.x + c5.x) + (c6.x + c7.x));
            acc.w += ((c0.y + c1.y) + (c2.y + c3.y)) + ((c4.y + c5.y) + (c6.y + c7.y));
        }
        for (; t < cnt; ++t) {
            int r = __shfl(rid, sb + t, 64);
            union { uint2 u; __half2 h[2]; } v;
            v.u = *(const uint2*)(h1p + ((size_t)r << 6) + fl);
            float2 f0 = __half22float2(v.h[0]), f1 = __half22float2(v.h[1]);
            acc.x += f0.x; acc.y += f0.y; acc.z += f1.x; acc.w += f1.y;
        }
    }
    float dn = dinv[nd];
    float4 bb = *(const float4*)(b1 + fl);
    float4 gg = *(const float4*)(g1 + fl);
    float4 ee = *(const float4*)(be1 + fl);
    float4 mm = *(const float4*)(rm1 + fl);
    float4 vv = *(const float4*)(rv1 + fl);
    float4 o;
    o.x = fmaxf((dn * acc.x + bb.x - mm.x) * (gg.x * rsqrtf(vv.x + BN_EPS)) + ee.x, 0.f);
    o.y = fmaxf((dn * acc.y + bb.y - mm.y) * (gg.y * rsqrtf(vv.y + BN_EPS)) + ee.y, 0.f);
    o.z = fmaxf((dn * acc.z + bb.z - mm.z) * (gg.z * rsqrtf(vv.z + BN_EPS)) + ee.z, 0.f);
    o.w = fmaxf((dn * acc.w + bb.w - mm.w) * (gg.w * rsqrtf(vv.w + BN_EPS)) + ee.w, 0.f);
    // ---- fused gemm2: h2p[nd][f2] = fp16( dinv[nd] * sum_k act[k]*W2[k][f2] ) ----
    float a0 = 0.f, a1 = 0.f;
#pragma unroll
    for (int k4 = 0; k4 < 16; ++k4) {
        int src = sb + k4;
        float ax = __shfl(o.x, src, 64);
        float ay = __shfl(o.y, src, 64);
        float az = __shfl(o.z, src, 64);
        float aw = __shfl(o.w, src, 64);
        int kb = k4 << 2;
        float2 w0 = *(const float2*)&W2p[((kb + 0) << 5) + (l16 << 1)];
        float2 w1 = *(const float2*)&W2p[((kb + 1) << 5) + (l16 << 1)];
        float2 w2 = *(const float2*)&W2p[((kb + 2) << 5) + (l16 << 1)];
        float2 w3 = *(const float2*)&W2p[((kb + 3) << 5) + (l16 << 1)];
        a0 = fmaf(ax, w0.x, a0); a1 = fmaf(ax, w0.y, a1);
        a0 = fmaf(ay, w1.x, a0); a1 = fmaf(ay, w1.y, a1);
        a0 = fmaf(az, w2.x, a0); a1 = fmaf(az, w2.y, a1);
        a0 = fmaf(aw, w3.x, a0); a1 = fmaf(aw, w3.y, a1);
    }
    h2p[((size_t)nd << 5) + l16] = __float2half(dn * a0);
    h2p[((size_t)nd << 5) + 16 + l16] = __float2half(dn * a1);
}

// ---------- gather layer 2 (fp16 rows): 8 nodes/wave, lane = 4 feats + fused FC ----------
__global__ __launch_bounds__(256) void k_gather2(const __half* __restrict__ h2p, const int* __restrict__ offs,
                                                 const unsigned short* __restrict__ csr, const float* __restrict__ dinv,
                                                 const float* __restrict__ b2, const float* __restrict__ g2,
                                                 const float* __restrict__ be2, const float* __restrict__ rm2,
                                                 const float* __restrict__ rv2, const float* __restrict__ fcW,
                                                 const float* __restrict__ fcb, float* __restrict__ out, int N) {
    int wid = (blockIdx.x * 256 + threadIdx.x) >> 6;
    int lane = threadIdx.x & 63;
    int sub = lane >> 3;              // node slot 0..7
    int l8 = lane & 7;
    int fl = l8 << 2;                 // feature base 0..28
    int nd = wid * 8 + sub;
    bool ok = nd < N;
    if (!ok) nd = N - 1;
    int start = offs[nd], end = offs[nd + 1];
    float4 acc;
    {   // self loop
        union { uint2 u; __half2 h[2]; } v;
        v.u = *(const uint2*)(h2p + ((size_t)nd << 5) + fl);
        float2 f0 = __half22float2(v.h[0]), f1 = __half22float2(v.h[1]);
        acc = make_float4(f0.x, f0.y, f1.x, f1.y);
    }
    int sb = sub << 3;
    for (int j = start; j < end; j += 8) {
        int rid = (j + l8 < end) ? (int)csr[j + l8] : 0;
        int cnt = end - j; if (cnt > 8) cnt = 8;
        int t = 0;
        for (; t + 7 < cnt; t += 8) {
            int r0 = __shfl(rid, sb + 0, 64), r1 = __shfl(rid, sb + 1, 64);
            int r2 = __shfl(rid, sb + 2, 64), r3 = __shfl(rid, sb + 3, 64);
            int r4 = __shfl(rid, sb + 4, 64), r5 = __shfl(rid, sb + 5, 64);
            int r6 = __shfl(rid, sb + 6, 64), r7 = __shfl(rid, sb + 7, 64);
            union { uint2 u; __half2 h[2]; } v0, v1, v2, v3, v4, v5, v6, v7;
            v0.u = *(const uint2*)(h2p + ((size_t)r0 << 5) + fl);
            v1.u = *(const uint2*)(h2p + ((size_t)r1 << 5) + fl);
            v2.u = *(const uint2*)(h2p + ((size_t)r2 << 5) + fl);
            v3.u = *(const uint2*)(h2p + ((size_t)r3 << 5) + fl);
            v4.u = *(const uint2*)(h2p + ((size_t)r4 << 5) + fl);
            v5.u = *(const uint2*)(h2p + ((size_t)r5 << 5) + fl);
            v6.u = *(const uint2*)(h2p + ((size_t)r6 << 5) + fl);
            v7.u = *(const uint2*)(h2p + ((size_t)r7 << 5) + fl);
            float2 a0 = __half22float2(v0.h[0]), a1 = __half22float2(v1.h[0]);
            float2 a2 = __half22float2(v2.h[0]), a3 = __half22float2(v3.h[0]);
            float2 a4 = __half22float2(v4.h[0]), a5 = __half22float2(v5.h[0]);
            float2 a6 = __half22float2(v6.h[0]), a7 = __half22float2(v7.h[0]);
            acc.x += ((a0.x + a1.x) + (a2.x + a3.x)) + ((a4.x + a5.x) + (a6.x + a7.x));
            acc.y += ((a0.y + a1.y) + (a2.y + a3.y)) + ((a4.y + a5.y) + (a6.y + a7.y));
            float2 c0 = __half22float2(v0.h[1]), c1 = __half22float2(v1.h[1]);
            float2 c2 = __half22float2(v2.h[1]), c3 = __half22float2(v3.h[1]);
            float2 c4 = __half22float2(v4.h[1]), c5 = __half22float2(v5.h[1]);
            float2 c6 = __half22float2(v6.h[1]), c7 = __half22float2(v7.h[1]);
            acc.z += ((c0.x + c1.x) + (c2.x + c3.x)) + ((c4.x + c5.x) + (c6.x + c7.x));
            acc.w += ((c0.y + c1.y) + (c2.y + c3.y)) + ((c4.y + c5.y) + (c6.y + c7.y));
        }
        for (; t < cnt; ++t) {
            int r = __shfl(rid, sb + t, 64);
            union { uint2 u; __half2 h[2]; } v;
            v.u = *(const uint2*)(h2p + ((size_t)r << 5) + fl);
            float2 f0 = __half22float2(v.h[0]), f1 = __half22float2(v.h[1]);
            acc.x += f0.x; acc.y += f0.y; acc.z += f1.x; acc.w += f1.y;
        }
    }
    float dn = dinv[nd];
    float4 bb = *(const float4*)(b2 + fl);
    float4 gg = *(const float4*)(g2 + fl);
    float4 ee = *(const float4*)(be2 + fl);
    float4 mm = *(const float4*)(rm2 + fl);
    float4 vv = *(const float4*)(rv2 + fl);
    float4 ww = *(const float4*)(fcW + fl);
    float s;
    s  = fmaxf((dn * acc.x + bb.x - mm.x) * (gg.x * rsqrtf(vv.x + BN_EPS)) + ee.x, 0.f) * ww.x;
    s += fmaxf((dn * acc.y + bb.y - mm.y) * (gg.y * rsqrtf(vv.y + BN_EPS)) + ee.y, 0.f) * ww.y;
    s += fmaxf((dn * acc.z + bb.z - mm.z) * (gg.z * rsqrtf(vv.z + BN_EPS)) + ee.z, 0.f) * ww.z;
    s += fmaxf((dn * acc.w + bb.w - mm.w) * (gg.w * rsqrtf(vv.w + BN_EPS)) + ee.w, 0.f) * ww.w;
    s += __shfl_down(s, 4, 8);
    s += __shfl_down(s, 2, 8);
    s += __shfl_down(s, 1, 8);
    if (ok && l8 == 0) out[nd] = s + fcb[0];
}

extern "C" void kernel_launch(void* const* d_in, const int* in_sizes, int n_in,
                              void* d_out, int out_size, void* d_ws, size_t ws_size,
                              hipStream_t stream) {
    const float* x   = (const float*)d_in[0];
    const int*   ei  = (const int*)d_in[1];
    const float* W1  = (const float*)d_in[2];
    const float* b1  = (const float*)d_in[3];
    const float* W2  = (const float*)d_in[4];
    const float* b2  = (const float*)d_in[5];
    const float* fcW = (const float*)d_in[6];
    const float* fcb = (const float*)d_in[7];
    const float* g1  = (const float*)d_in[8];
    const float* be1 = (const float*)d_in[9];
    const float* rm1 = (const float*)d_in[10];
    const float* rv1 = (const float*)d_in[11];
    const float* g2  = (const float*)d_in[12];
    const float* be2 = (const float*)d_in[13];
    const float* rm2 = (const float*)d_in[14];
    const float* rv2 = (const float*)d_in[15];
    float* out = (float*)d_out;

    const int N = N_NODES, E = N_EDGES;
    const int NB = (N + 255) / 256;           // 196 scan blocks
    const int EB = (E / 4 + 255) / 256;       // 782 edge blocks
    const int GB = (N + 63) / 64;             // 782 gemm1 blocks (== EB)
    const int SB = (N * HID / 8 + 255) / 256; // 1563 scale blocks

    char* base = (char*)d_ws;
    int*            deg4 = (int*)(base);                      // 4 planes x NP ints (802816 B)
    int*            offs = (int*)(base + 802816);             // N+1 ints
    int4*           off4 = (int4*)(base + 1003520);           // N int4 (800 KB)
    float*          dinv = (float*)(base + 1806336);          // N floats
    int*            bsum = (int*)(base + 2007040);            // 256 ints
    unsigned short* rank = (unsigned short*)(base + 2008064); // E ushort (1.6 MB)
    unsigned short* csr  = (unsigned short*)(base + 3608576); // E ushort (1.6 MB)
    __half*         h1p  = (__half*)(base + 5209088);         // N*64 halves (6.4 MB)
    __half*         h2p  = (__half*)(base + 11609088);        // N*32 halves (3.2 MB)

    hipMemsetAsync(deg4, 0, 4 * NP * sizeof(int), stream);

    // fused: even blocks = gemm1-unscaled (GB), odd blocks = degrank (EB); EB == GB
    k_degrank_gemm1<<<EB + GB, 256, 0, stream>>>(ei, deg4, rank, x, W1, h1p, E, N);
    k_scan1<<<NB, 256, 0, stream>>>(deg4, bsum, dinv, N);
    k_scan3<<<NB, 256, 0, stream>>>(deg4, bsum, offs, off4, N, NB);
    // fused: even blocks = h1 scale (SB), odd blocks = fillr (EB)
    k_fillr_scale<<<2 * SB, 256, 0, stream>>>(ei, rank, off4, csr, h1p, dinv, E, N, EB);

    k_gather1<<<(N / 4) * 64 / 256, 256, 0, stream>>>(h1p, offs, csr, dinv, b1, g1, be1, rm1, rv1, W2, h2p, N);
    k_gather2<<<((N + 7) / 8 * 64 + 255) / 256, 256, 0, stream>>>(h2p, offs, csr, dinv, b2, g2, be2, rm2, rv2, fcW, fcb, out, N);
}